// Round 2
// baseline (605.125 us; speedup 1.0000x reference)
//
#include <hip/hip_runtime.h>

// Problem: B=8, C=16, H=32, W=32 -> N=1024, Ho=Wo=16, P=256
// d_out layout: mu_p [128*256 = 32768 f32] then sigma_p [128*256*256 = 8388608 f32]
// No d_ws use (previous round crashed — assumed ws_size >= 128KiB, likely smaller).

#define BC    128
#define WDIM  32
#define NP    256
#define NN    1024

// One fused kernel, 512 blocks x 256 threads.
//   bc = blockIdx.x >> 2 ; i0 = (blockIdx.x & 3) * 64  (output-row chunk)
// Each block recomputes the 256 pooled argmax indices for its (b,c) into LDS
// (redundant x4 across blocks sharing a bc — mu is 512 KB, L2-resident).
// Block with i0==0 also writes mu_p. Then 64 gather rows: scattered 4B load,
// coalesced 4B store.
__global__ __launch_bounds__(256) void fused_kernel(
    const float* __restrict__ mu,
    const float* __restrict__ sigma,
    float* __restrict__ out_mu,     // [BC*NP]
    float* __restrict__ out_sigma)  // [BC*NP*NP]
{
    int bc = blockIdx.x >> 2;
    int i0 = (blockIdx.x & 3) * 64;
    int t  = threadIdx.x;           // pooled position / output column

    __shared__ int s_idx[NP];

    // --- pooled max + first-occurrence argmax for position t ---
    int ho = t >> 4, wo = t & 15;
    const float* m = mu + (size_t)bc * NN;
    int r0 = 2 * ho, c0 = 2 * wo;
    float v00 = m[r0 * WDIM + c0];
    float v01 = m[r0 * WDIM + c0 + 1];
    float v10 = m[(r0 + 1) * WDIM + c0];
    float v11 = m[(r0 + 1) * WDIM + c0 + 1];
    float best = v00; int k = 0;
    if (v01 > best) { best = v01; k = 1; }
    if (v10 > best) { best = v10; k = 2; }
    if (v11 > best) { best = v11; k = 3; }
    int fidx = (r0 + (k >> 1)) * WDIM + (c0 + (k & 1));
    s_idx[t] = fidx;
    if (i0 == 0) out_mu[bc * NP + t] = best;
    __syncthreads();

    // --- gather: sigma_p[bc, i, t] = sigma[bc, idx[i], idx[t]] ---
    int cj = s_idx[t];
    const float* sg = sigma + (size_t)bc * NN * NN;
    float* ob = out_sigma + ((size_t)bc * NP + i0) * NP;

#pragma unroll 4
    for (int ii = 0; ii < 64; ++ii) {
        int ri = s_idx[i0 + ii];                  // LDS broadcast (wave-uniform value)
        ob[(size_t)ii * NP + t] = sg[(size_t)ri * NN + cj];
    }
}

extern "C" void kernel_launch(void* const* d_in, const int* in_sizes, int n_in,
                              void* d_out, int out_size, void* d_ws, size_t ws_size,
                              hipStream_t stream) {
    const float* mu    = (const float*)d_in[0];
    const float* sigma = (const float*)d_in[1];
    float* out = (float*)d_out;
    fused_kernel<<<512, 256, 0, stream>>>(mu, sigma, out, out + BC * NP);
}